// Round 2
// 655.833 us; speedup vs baseline: 1.0584x; 1.0584x over previous
//
#include <hip/hip_runtime.h>
#include <cstdint>
#include <cstddef>

typedef __attribute__((ext_vector_type(8))) short bf16x8;
typedef __attribute__((ext_vector_type(4))) float f32x4;

__device__ __forceinline__ ushort f2b(float f) {
    union { float f; uint32_t u; } v; v.f = f;
    uint32_t r = (v.u + 0x7fffu + ((v.u >> 16) & 1u)) >> 16;
    return (ushort)r;
}
__device__ __forceinline__ float b2f(ushort b) {
    union { uint32_t u; float f; } v; v.u = ((uint32_t)b) << 16;
    return v.f;
}

// direct global->LDS async copy, 16B per lane. LDS dest must be wave-uniform base.
__device__ __forceinline__ void gll16(const void* g, void* l) {
    __builtin_amdgcn_global_load_lds((const __attribute__((address_space(1))) void*)g,
                                     (__attribute__((address_space(3))) void*)l, 16, 0, 0);
}

// ================= CSR build: two-level bucket sort =================
__global__ __launch_bounds__(256) void hist_kernel(const int* __restrict__ rows,
                                                   int* __restrict__ bhist, int E, int nb) {
    __shared__ int h[512];
    for (int i = threadIdx.x; i < nb; i += 256) h[i] = 0;
    __syncthreads();
    int stride = gridDim.x * blockDim.x;
    for (int e = blockIdx.x * blockDim.x + threadIdx.x; e < E; e += stride)
        atomicAdd(&h[rows[e] >> 7], 1);
    __syncthreads();
    for (int i = threadIdx.x; i < nb; i += 256)
        if (h[i]) atomicAdd(&bhist[i], h[i]);
}

__global__ __launch_bounds__(512) void scan512(const int* __restrict__ bhist,
                                               int* __restrict__ boff, int* __restrict__ gcur,
                                               int* __restrict__ rp, int nb, int E, int N) {
    __shared__ int sm[512];
    int v = ((int)threadIdx.x < nb) ? bhist[threadIdx.x] : 0;
    sm[threadIdx.x] = v;
    __syncthreads();
    for (int off = 1; off < 512; off <<= 1) {
        int t = ((int)threadIdx.x >= off) ? sm[threadIdx.x - off] : 0;
        __syncthreads();
        sm[threadIdx.x] += t;
        __syncthreads();
    }
    if ((int)threadIdx.x < nb) {
        int e0 = sm[threadIdx.x] - v;
        boff[threadIdx.x] = e0;
        gcur[threadIdx.x] = e0;
    }
    if (threadIdx.x == 0) { boff[nb] = E; rp[N] = E; }
}

__global__ __launch_bounds__(256) void binpass(const int* __restrict__ rows,
                                               const int* __restrict__ cols,
                                               const float* __restrict__ avals,
                                               int* __restrict__ gcur,
                                               uint2* __restrict__ tmp, int E, int nb) {
    __shared__ int hist[512];
    __shared__ int base[512];
    int e0 = blockIdx.x * 4096;
    int nE = min(4096, E - e0);
    for (int i = threadIdx.x; i < nb; i += 256) hist[i] = 0;
    __syncthreads();
    for (int i = threadIdx.x; i < nE; i += 256)
        atomicAdd(&hist[rows[e0 + i] >> 7], 1);
    __syncthreads();
    for (int i = threadIdx.x; i < nb; i += 256) {
        int c = hist[i];
        if (c) base[i] = atomicAdd(&gcur[i], c);
        hist[i] = 0;
    }
    __syncthreads();
    for (int i = threadIdx.x; i < nE; i += 256) {
        int r = rows[e0 + i];
        int b = r >> 7;
        int loc = atomicAdd(&hist[b], 1);
        uint2 t;
        t.x = ((uint32_t)r << 16) | (uint32_t)cols[e0 + i];
        t.y = __float_as_uint(avals[e0 + i]);
        tmp[base[b] + loc] = t;
    }
}

__global__ __launch_bounds__(256) void bucketpass(const uint2* __restrict__ tmp,
                                                  const int* __restrict__ boff,
                                                  int* __restrict__ rp,
                                                  int* __restrict__ col_s,
                                                  float* __restrict__ a_s, int N) {
    __shared__ int cnt[128];
    __shared__ int pre[128];
    int b = blockIdx.x;
    int r0 = b << 7;
    int nr = min(128, N - r0);
    int t0 = boff[b], t1 = boff[b + 1];
    if ((int)threadIdx.x < 128) cnt[threadIdx.x] = 0;
    __syncthreads();
    for (int i = t0 + (int)threadIdx.x; i < t1; i += 256)
        atomicAdd(&cnt[(tmp[i].x >> 16) - r0], 1);
    __syncthreads();
    if ((int)threadIdx.x < 128) pre[threadIdx.x] = cnt[threadIdx.x];
    __syncthreads();
    for (int off = 1; off < 128; off <<= 1) {
        int t = ((int)threadIdx.x >= off && (int)threadIdx.x < 128) ? pre[threadIdx.x - off] : 0;
        __syncthreads();
        if ((int)threadIdx.x < 128) pre[threadIdx.x] += t;
        __syncthreads();
    }
    if ((int)threadIdx.x < nr) {
        int ex = pre[threadIdx.x] - cnt[threadIdx.x];
        rp[r0 + threadIdx.x] = t0 + ex;
        cnt[threadIdx.x] = t0 + ex;
    }
    __syncthreads();
    for (int i = t0 + (int)threadIdx.x; i < t1; i += 256) {
        uint2 t = tmp[i];
        int lr = (int)(t.x >> 16) - r0;
        int pos = atomicAdd(&cnt[lr], 1);
        col_s[pos] = (int)(t.x & 0xffffu);
        a_s[pos] = __uint_as_float(t.y);
    }
}

// ---------------- fp32 -> bf16 converts ----------------
__global__ void f2b4_kernel(const float* __restrict__ src, ushort* __restrict__ dst, int n4) {
    int i = blockIdx.x * blockDim.x + threadIdx.x;
    if (i < n4) {
        float4 v = ((const float4*)src)[i];
        ushort4 o;
        o.x = f2b(v.x); o.y = f2b(v.y); o.z = f2b(v.z); o.w = f2b(v.w);
        ((ushort4*)dst)[i] = o;
    }
}

// W0 [256,512] -> W0h bf16, Wt0h = W0^T bf16 [512,256]; W1 [128,256] -> W1h bf16.
__global__ __launch_bounds__(256) void prep_weights(const float* __restrict__ W0,
                                                    const float* __restrict__ W1,
                                                    ushort* __restrict__ W0h,
                                                    ushort* __restrict__ W1h,
                                                    ushort* __restrict__ Wt0h) {
    int i = blockIdx.x * 256 + threadIdx.x;   // 0..32767
    float4 v = ((const float4*)W0)[i];
    ushort4 o;
    o.x = f2b(v.x); o.y = f2b(v.y); o.z = f2b(v.z); o.w = f2b(v.w);
    ((ushort4*)W0h)[i] = o;
    int r = (i * 4) >> 9;          // W0 row
    int c = (i * 4) & 511;         // W0 col (4 consecutive, same row)
    Wt0h[(size_t)(c + 0) * 256 + r] = o.x;
    Wt0h[(size_t)(c + 1) * 256 + r] = o.y;
    Wt0h[(size_t)(c + 2) * 256 + r] = o.z;
    Wt0h[(size_t)(c + 3) * 256 + r] = o.w;
    if (i < 8192) {
        float4 w = ((const float4*)W1)[i];
        ushort4 p;
        p.x = f2b(w.x); p.y = f2b(w.y); p.z = f2b(w.z); p.w = f2b(w.w);
        ((ushort4*)W1h)[i] = p;
    }
}

// ---------------- bf16 MFMA NT GEMM, global_load_lds staging ----------------
// C[M,Dout] = A[M,K] @ B[Dout,K]^T + bias.  A,B bf16 row-major, K%64==0, Dout%128==0.
// 128x128 tile, 256 threads = 4 waves (64x64 quadrant each), BK=64.
// LDS linear [128][64] ushort per matrix; 16B chunk at (row, c) stores global chunk
// (row, c ^ (row&7)) -> ds_read_b128 fragment reads are 2-way (free) instead of 8-way.
__global__ __launch_bounds__(256) void gemm_bf16(const ushort* __restrict__ A,
                                                 const ushort* __restrict__ B,
                                                 const float* __restrict__ bias,
                                                 float* __restrict__ Cf,
                                                 ushort* __restrict__ Ch,
                                                 int M, int K, int Dout) {
    __shared__ ushort As[128 * 64];
    __shared__ ushort Bs[128 * 64];
    int bm = blockIdx.y * 128, bn = blockIdx.x * 128;
    int tid = threadIdx.x;
    int w = tid >> 6, l = tid & 63;
    int wm = (w & 1) * 64, wn = (w >> 1) * 64;
    int lm = l & 15, quad = l >> 4;
    int wslot = tid & 192;               // wave-uniform slot base (0,64,128,192)

    f32x4 acc[4][4] = {};

    for (int k0 = 0; k0 < K; k0 += 64) {
#pragma unroll
        for (int it = 0; it < 4; ++it) {
            int slot = it * 256 + tid;       // 0..1023: one 16B chunk each
            int row = slot >> 3;             // 0..127
            int qg = ((slot & 7) ^ (row & 7)) * 8;   // pre-swizzled source chunk
            int ga = bm + row; if (ga > M - 1) ga = M - 1;
            gll16(A + (size_t)ga * K + k0 + qg, As + (size_t)(it * 256 + wslot) * 8);
            gll16(B + (size_t)(bn + row) * K + k0 + qg, Bs + (size_t)(it * 256 + wslot) * 8);
        }
        __syncthreads();
#pragma unroll
        for (int ks = 0; ks < 2; ++ks) {
            bf16x8 af[4], bfr[4];
#pragma unroll
            for (int i = 0; i < 4; ++i) {
                int r = wm + i * 16 + lm;
                af[i] = *(const bf16x8*)&As[r * 64 + (((ks * 4 + quad) ^ (r & 7)) * 8)];
            }
#pragma unroll
            for (int j = 0; j < 4; ++j) {
                int r = wn + j * 16 + lm;
                bfr[j] = *(const bf16x8*)&Bs[r * 64 + (((ks * 4 + quad) ^ (r & 7)) * 8)];
            }
#pragma unroll
            for (int i = 0; i < 4; ++i)
#pragma unroll
                for (int j = 0; j < 4; ++j)
                    acc[i][j] = __builtin_amdgcn_mfma_f32_16x16x32_bf16(af[i], bfr[j], acc[i][j], 0, 0, 0);
        }
        __syncthreads();
    }

    float bv[4] = {0.f, 0.f, 0.f, 0.f};
    if (bias) {
#pragma unroll
        for (int j = 0; j < 4; ++j) bv[j] = bias[bn + wn + j * 16 + lm];
    }
#pragma unroll
    for (int i = 0; i < 4; ++i) {
#pragma unroll
        for (int r = 0; r < 4; ++r) {
            int row = bm + wm + i * 16 + quad * 4 + r;
            if (row < M) {
#pragma unroll
                for (int j = 0; j < 4; ++j) {
                    int col = bn + wn + j * 16 + lm;
                    float v = acc[i][j][r] + bv[j];
                    if (Cf) Cf[(size_t)row * Dout + col] = v;
                    if (Ch) Ch[(size_t)row * Dout + col] = f2b(v);
                }
            }
        }
    }
}

// ---------------- f1/f2 = M @ va, M @ vb for d=256 (single pass, 4 rows/block) ----------------
__global__ __launch_bounds__(256) void fvec256_kernel(const ushort* __restrict__ Mh,
                                                      const float* __restrict__ va,
                                                      const float* __restrict__ vb,
                                                      float* __restrict__ f1,
                                                      float* __restrict__ f2, int N) {
    int n = blockIdx.x * 4 + (threadIdx.x >> 6);
    if (n >= N) return;
    int lane = threadIdx.x & 63;
    ushort4 m4 = ((const ushort4*)(Mh + (size_t)n * 256))[lane];
    float4 a4 = ((const float4*)va)[lane];
    float4 b4 = ((const float4*)vb)[lane];
    float m0 = b2f(m4.x), m1 = b2f(m4.y), m2 = b2f(m4.z), m3 = b2f(m4.w);
    float s1 = m0 * a4.x + m1 * a4.y + m2 * a4.z + m3 * a4.w;
    float s2 = m0 * b4.x + m1 * b4.y + m2 * b4.z + m3 * b4.w;
#pragma unroll
    for (int off = 32; off > 0; off >>= 1) {
        s1 += __shfl_xor(s1, off);
        s2 += __shfl_xor(s2, off);
    }
    if (lane == 0) { f1[n] = s1; f2[n] = s2; }
}

// ---------------- edge attention, single sweep ----------------
// Softmax is shift-invariant and sigmoid in (0,1) bounds exp <= e: no max pass needed.
// Stores unnormalized e; per-row 1/sum goes to rs[] and is applied in spmm.
__global__ __launch_bounds__(256) void att2_kernel(const int* __restrict__ rp,
                                                   const int* __restrict__ col_s,
                                                   const float* __restrict__ a_s,
                                                   const float* __restrict__ f1,
                                                   const float* __restrict__ f2,
                                                   float* __restrict__ att,
                                                   float* __restrict__ rs, int N) {
    int r = blockIdx.x * 4 + (threadIdx.x >> 6);
    if (r >= N) return;
    int lane = threadIdx.x & 63;
    int beg = rp[r], end = rp[r + 1];
    float fr = f1[r];
    float s = 0.f;
    for (int j = beg + lane; j < end; j += 64) {
        float x = a_s[j] * (fr + f2[col_s[j]]);
        float v = 1.f / (1.f + __expf(-x));
        float e = __expf(v);
        att[j] = e;
        s += e;
    }
#pragma unroll
    for (int off = 32; off > 0; off >>= 1) s += __shfl_xor(s, off);
    if (lane == 0) rs[r] = (end > beg) ? 1.f / s : 0.f;
}

// ---------------- SpMM d=128 (CSR gather, 16 lanes/row x 16B, fp32 accumulate) ----------------
// acc = (sum_e att[e]*H[col]) * rs[row] + bias; optional fused f1/f2 = acc . va/vb.
__global__ __launch_bounds__(256) void spmm128(const int* __restrict__ rp,
                                               const int* __restrict__ col_s,
                                               const float* __restrict__ att,
                                               const float* __restrict__ rs,
                                               const ushort* __restrict__ H,
                                               const float* __restrict__ bias,
                                               const float* __restrict__ va,
                                               const float* __restrict__ vb,
                                               float* __restrict__ f1,
                                               float* __restrict__ f2,
                                               ushort* __restrict__ Oh,
                                               float* __restrict__ Of, int N) {
    int r = blockIdx.x * 16 + (threadIdx.x >> 4);
    if (r >= N) return;
    int lane = threadIdx.x & 15;
    int beg = rp[r], end = rp[r + 1];
    float acc[8] = {0.f, 0.f, 0.f, 0.f, 0.f, 0.f, 0.f, 0.f};
    const uint4* H4 = (const uint4*)H;
#define FMA8(h, wgt) { \
        acc[0] += (wgt) * b2f((ushort)((h).x & 0xffffu)); \
        acc[1] += (wgt) * b2f((ushort)((h).x >> 16)); \
        acc[2] += (wgt) * b2f((ushort)((h).y & 0xffffu)); \
        acc[3] += (wgt) * b2f((ushort)((h).y >> 16)); \
        acc[4] += (wgt) * b2f((ushort)((h).z & 0xffffu)); \
        acc[5] += (wgt) * b2f((ushort)((h).z >> 16)); \
        acc[6] += (wgt) * b2f((ushort)((h).w & 0xffffu)); \
        acc[7] += (wgt) * b2f((ushort)((h).w >> 16)); }
    int j = beg;
    for (; j + 4 <= end; j += 4) {
        int c0 = col_s[j], c1 = col_s[j + 1], c2 = col_s[j + 2], c3 = col_s[j + 3];
        float w0 = att[j], w1 = att[j + 1], w2 = att[j + 2], w3 = att[j + 3];
        uint4 h0 = H4[(size_t)c0 * 16 + lane];
        uint4 h1 = H4[(size_t)c1 * 16 + lane];
        uint4 h2 = H4[(size_t)c2 * 16 + lane];
        uint4 h3 = H4[(size_t)c3 * 16 + lane];
        FMA8(h0, w0) FMA8(h1, w1) FMA8(h2, w2) FMA8(h3, w3)
    }
    for (; j < end; ++j) {
        uint4 h = H4[(size_t)col_s[j] * 16 + lane];
        float w0 = att[j];
        FMA8(h, w0)
    }
#undef FMA8
    float rsv = rs[r];
#pragma unroll
    for (int k = 0; k < 8; ++k) acc[k] *= rsv;
    if (bias) {
        const float4* b4 = (const float4*)(bias + lane * 8);
        float4 ba = b4[0], bb = b4[1];
        acc[0] += ba.x; acc[1] += ba.y; acc[2] += ba.z; acc[3] += ba.w;
        acc[4] += bb.x; acc[5] += bb.y; acc[6] += bb.z; acc[7] += bb.w;
    }
    if (va) {
        const float4* a4 = (const float4*)(va + lane * 8);
        const float4* c4 = (const float4*)(vb + lane * 8);
        float4 va0 = a4[0], va1 = a4[1], vb0 = c4[0], vb1 = c4[1];
        float p1 = acc[0] * va0.x + acc[1] * va0.y + acc[2] * va0.z + acc[3] * va0.w
                 + acc[4] * va1.x + acc[5] * va1.y + acc[6] * va1.z + acc[7] * va1.w;
        float p2 = acc[0] * vb0.x + acc[1] * vb0.y + acc[2] * vb0.z + acc[3] * vb0.w
                 + acc[4] * vb1.x + acc[5] * vb1.y + acc[6] * vb1.z + acc[7] * vb1.w;
#pragma unroll
        for (int off = 8; off > 0; off >>= 1) {
            p1 += __shfl_xor(p1, off);
            p2 += __shfl_xor(p2, off);
        }
        if (lane == 0) { f1[r] = p1; f2[r] = p2; }
    }
    if (Oh) {
        uint4 o;
        o.x = (uint32_t)f2b(acc[0]) | ((uint32_t)f2b(acc[1]) << 16);
        o.y = (uint32_t)f2b(acc[2]) | ((uint32_t)f2b(acc[3]) << 16);
        o.z = (uint32_t)f2b(acc[4]) | ((uint32_t)f2b(acc[5]) << 16);
        o.w = (uint32_t)f2b(acc[6]) | ((uint32_t)f2b(acc[7]) << 16);
        ((uint4*)Oh)[(size_t)r * 16 + lane] = o;
    }
    if (Of) {
        float4* O4 = (float4*)Of;
        O4[(size_t)r * 32 + lane * 2]     = make_float4(acc[0], acc[1], acc[2], acc[3]);
        O4[(size_t)r * 32 + lane * 2 + 1] = make_float4(acc[4], acc[5], acc[6], acc[7]);
    }
}

// ---------------- driver ----------------
// Algebra (all ops linear; softmax rows sum to 1 so bias commutes through spmm):
//   M0 = X@W0^T + b0                         [N,256]
//   P  = M0@W1^T                             [N,128]
//   M1 = spmm(att0, P) + b1                  [N,128]
//   H2 = spmm(att1, M1)                      [N,128]  (final_H)
//   out = spmm(att0, spmm(att1, H2)) @ (W1@W0)        [N,512]
extern "C" void kernel_launch(void* const* d_in, const int* in_sizes, int n_in,
                              void* d_out, int out_size, void* d_ws, size_t ws_size,
                              hipStream_t stream) {
    const float* X    = (const float*)d_in[0];
    const int*   erow = (const int*)d_in[1];
    const int*   ecol = (const int*)d_in[2];
    const float* aval = (const float*)d_in[3];
    const float* W0   = (const float*)d_in[4];
    const float* b0   = (const float*)d_in[5];
    const float* W1   = (const float*)d_in[6];
    const float* b1   = (const float*)d_in[7];
    const float* v00  = (const float*)d_in[8];
    const float* v01  = (const float*)d_in[9];
    const float* v10  = (const float*)d_in[10];
    const float* v11  = (const float*)d_in[11];

    const int D0 = 512, D1 = 256, D2 = 128;
    const int N = in_sizes[0] / D0;
    const int E = in_sizes[1];
    const int NB = (N + 127) / 128;
    float* out = (float*)d_out;

    char* ws = (char*)d_ws;
    size_t off = 0;
    auto alloc = [&](size_t bytes) {
        char* p = ws + off;
        off += (bytes + 255) & ~(size_t)255;
        return p;
    };
    ushort* Xh   = (ushort*)alloc((size_t)N * D0 * 2);
    ushort* M0h  = (ushort*)alloc((size_t)N * D1 * 2);
    ushort* Ph   = (ushort*)alloc((size_t)N * D2 * 2);  // P / S1
    ushort* M1h  = (ushort*)alloc((size_t)N * D2 * 2);
    ushort* H2h  = (ushort*)alloc((size_t)N * D2 * 2);
    ushort* S0h  = (ushort*)alloc((size_t)N * D2 * 2);
    ushort* W0h  = (ushort*)alloc((size_t)D1 * D0 * 2); // [256,512]
    ushort* W1h  = (ushort*)alloc((size_t)D2 * D1 * 2); // [128,256]
    ushort* Wt0h = (ushort*)alloc((size_t)D0 * D1 * 2); // W0^T [512,256]
    ushort* WfTh = (ushort*)alloc((size_t)D0 * D2 * 2); // (W1@W0)^T [512,128]
    float* att0  = (float*)alloc((size_t)E * 4);
    float* att1  = (float*)alloc((size_t)E * 4);
    float* a_s   = (float*)alloc((size_t)E * 4);
    float* f1    = (float*)alloc((size_t)N * 4);
    float* f2    = (float*)alloc((size_t)N * 4);
    float* rs0   = (float*)alloc((size_t)N * 4);
    float* rs1   = (float*)alloc((size_t)N * 4);
    int* rp      = (int*)alloc(((size_t)N + 1) * 4);
    int* col_s   = (int*)alloc((size_t)E * 4);
    uint2* tmp   = (uint2*)alloc((size_t)E * 8);
    int* bhist   = (int*)alloc(512 * 4);
    int* boff    = (int*)alloc(513 * 4);
    int* gcur    = (int*)alloc(512 * 4);

    // ---- CSR build ----
    hipMemsetAsync(bhist, 0, 512 * sizeof(int), stream);
    hist_kernel<<<256, 256, 0, stream>>>(erow, bhist, E, NB);
    scan512<<<1, 512, 0, stream>>>(bhist, boff, gcur, rp, NB, E, N);
    binpass<<<(E + 4095) / 4096, 256, 0, stream>>>(erow, ecol, aval, gcur, tmp, E, NB);
    bucketpass<<<NB, 256, 0, stream>>>(tmp, boff, rp, col_s, a_s, N);

    // ---- bf16 converts ----
    f2b4_kernel<<<((N * D0 / 4) + 255) / 256, 256, 0, stream>>>(X, Xh, N * D0 / 4);
    prep_weights<<<128, 256, 0, stream>>>(W0, W1, W0h, W1h, Wt0h);

    // ---- fused decoder weight: WfT[512,128] = (W1@W0)^T = gemm_nt(Wt0h, W1h) ----
    gemm_bf16<<<dim3(1, 4), 256, 0, stream>>>(Wt0h, W1h, nullptr, nullptr, WfTh, D0, D1, D2);

    const int gy = (N + 127) / 128;
    const int agrid = (N + 3) / 4;
    const int sgrid = (N + 15) / 16;

    // ---- encoder ----
    gemm_bf16<<<dim3(D1 / 128, gy), 256, 0, stream>>>(Xh, W0h, b0, nullptr, M0h, N, D0, D1); // M0
    fvec256_kernel<<<agrid, 256, 0, stream>>>(M0h, v00, v01, f1, f2, N);
    att2_kernel<<<agrid, 256, 0, stream>>>(rp, col_s, a_s, f1, f2, att0, rs0, N);
    gemm_bf16<<<dim3(1, gy), 256, 0, stream>>>(M0h, W1h, nullptr, nullptr, Ph, N, D1, D2);   // P
    // M1 = spmm(att0,P)+b1, with fused f1/f2 = M1 . v10/v11 (fp32, closer to ref)
    spmm128<<<sgrid, 256, 0, stream>>>(rp, col_s, att0, rs0, Ph, b1, v10, v11, f1, f2,
                                       M1h, nullptr, N);
    att2_kernel<<<agrid, 256, 0, stream>>>(rp, col_s, a_s, f1, f2, att1, rs1, N);
    // H2 = final_H: bf16 for decoder + fp32 straight into output tail
    spmm128<<<sgrid, 256, 0, stream>>>(rp, col_s, att1, rs1, M1h, nullptr,
                                       nullptr, nullptr, nullptr, nullptr,
                                       H2h, out + (size_t)N * D0, N);

    // ---- decoder (fully commuted) ----
    spmm128<<<sgrid, 256, 0, stream>>>(rp, col_s, att1, rs1, H2h, nullptr,
                                       nullptr, nullptr, nullptr, nullptr,
                                       Ph, nullptr, N);   // S1
    spmm128<<<sgrid, 256, 0, stream>>>(rp, col_s, att0, rs0, Ph, nullptr,
                                       nullptr, nullptr, nullptr, nullptr,
                                       S0h, nullptr, N);  // S0
    gemm_bf16<<<dim3(D0 / 128, gy), 256, 0, stream>>>(S0h, WfTh, nullptr, out, nullptr, N, D2, D0);
}